// Round 1
// baseline (544.396 us; speedup 1.0000x reference)
//
#include <hip/hip_runtime.h>
#include <math.h>

#define HH 96
#define WW 96
#define PP 9216   // H*W
#define CCH 256
#define BB 4
#define NHD 8
#define CH 32
#define NN 32     // B*HEADS

// ---------------------------------------------------------------------------
// GEMM: Y[b][o][p] = sum_c W[o][c] * X[b][c][p] (+ bias[o])
// tile 128o x 128p per 256-thread block; each thread 8o x 8p; c-chunks of 32.
// ---------------------------------------------------------------------------
__global__ __launch_bounds__(256)
void gemm_oc(const float* __restrict__ Wm, const float* __restrict__ X,
             float* __restrict__ Y, const float* __restrict__ bias) {
  __shared__ float Xt[32][128];
  __shared__ float Wt[32][136];  // [c][o], padded
  const int t = threadIdx.x;
  const int pblk = blockIdx.x * 128;
  const int oblk = blockIdx.y * 128;
  const int b = blockIdx.z;
  const float* Xb = X + (size_t)b * CCH * PP;
  float acc[8][8];
#pragma unroll
  for (int i = 0; i < 8; i++)
#pragma unroll
    for (int j = 0; j < 8; j++) acc[i][j] = 0.f;
  const int pgrp = t & 15;   // 16 groups x 8 pixels
  const int ogrp = t >> 4;   // 16 groups x 8 outputs

  for (int c0 = 0; c0 < CCH; c0 += 32) {
    // stage X tile: 32c x 128p
#pragma unroll
    for (int k = 0; k < 4; k++) {
      int i4 = t + k * 256;          // 0..1023 float4 slots
      int c = i4 >> 5;               // 32 float4 per row
      int p4 = i4 & 31;
      float4 v = *(const float4*)(Xb + (size_t)(c0 + c) * PP + pblk + p4 * 4);
      *(float4*)(&Xt[c][p4 * 4]) = v;
    }
    // stage W tile transposed: Wt[c][o]
#pragma unroll
    for (int k = 0; k < 4; k++) {
      int i4 = t + k * 256;
      int oo = i4 >> 3;              // 8 float4 per row of 32 c
      int c4 = i4 & 7;
      float4 v = *(const float4*)(Wm + (size_t)(oblk + oo) * CCH + c0 + c4 * 4);
      Wt[c4 * 4 + 0][oo] = v.x;
      Wt[c4 * 4 + 1][oo] = v.y;
      Wt[c4 * 4 + 2][oo] = v.z;
      Wt[c4 * 4 + 3][oo] = v.w;
    }
    __syncthreads();
#pragma unroll
    for (int c = 0; c < 32; c++) {
      float4 x0 = *(const float4*)(&Xt[c][pgrp * 8]);
      float4 x1 = *(const float4*)(&Xt[c][pgrp * 8 + 4]);
      float4 w0 = *(const float4*)(&Wt[c][ogrp * 8]);
      float4 w1 = *(const float4*)(&Wt[c][ogrp * 8 + 4]);
      float xs[8] = {x0.x, x0.y, x0.z, x0.w, x1.x, x1.y, x1.z, x1.w};
      float ws[8] = {w0.x, w0.y, w0.z, w0.w, w1.x, w1.y, w1.z, w1.w};
#pragma unroll
      for (int i = 0; i < 8; i++)
#pragma unroll
        for (int j = 0; j < 8; j++) acc[i][j] = fmaf(ws[i], xs[j], acc[i][j]);
    }
    __syncthreads();
  }
#pragma unroll
  for (int i = 0; i < 8; i++) {
    int o = oblk + ogrp * 8 + i;
    float bv = bias ? bias[o] : 0.f;
    float* Yp = Y + ((size_t)b * CCH + o) * PP + pblk + pgrp * 8;
    float4 v0 = {acc[i][0] + bv, acc[i][1] + bv, acc[i][2] + bv, acc[i][3] + bv};
    float4 v1 = {acc[i][4] + bv, acc[i][5] + bv, acc[i][6] + bv, acc[i][7] + bv};
    *(float4*)(Yp) = v0;
    *(float4*)(Yp + 4) = v1;
  }
}

// ---------------------------------------------------------------------------
// Attention core. Q,K,V are [n][c][p] flat (n<32, c<32). Writes O in-place
// into the Q buffer (each thread only reads Q at its own pixel first).
// k-position kk = i*3+j <-> offset (i-1, j-1), zero padding.
// ---------------------------------------------------------------------------
__global__ __launch_bounds__(256)
void attn_k(const float* __restrict__ Kbuf, const float* __restrict__ Vbuf,
            float* __restrict__ QObuf, const float* __restrict__ pe_dw,
            const float* __restrict__ pe_pw) {
  __shared__ float coef[81];
  if (threadIdx.x < 81)
    coef[threadIdx.x] = pe_pw[threadIdx.x] * pe_dw[threadIdx.x % 9];
  __syncthreads();
  const int x = blockIdx.x * 32 + (threadIdx.x & 31);
  const int y = blockIdx.y * 8 + (threadIdx.x >> 5);
  const int n = blockIdx.z;
  const size_t base = (size_t)n * CH * PP;
  const float* Kn = Kbuf + base;
  const float* Vn = Vbuf + base;
  float* Qn = QObuf + base;
  const int p = y * WW + x;

  float q[CH];
#pragma unroll
  for (int c = 0; c < CH; c++) q[c] = Qn[c * PP + p];

  int pp[9];
  bool val[9];
  float f[9];
#pragma unroll
  for (int kk = 0; kk < 9; kk++) {
    int dy = kk / 3 - 1, dx = kk % 3 - 1;
    int yy = y + dy, xx = x + dx;
    val[kk] = (yy >= 0 && yy < HH && xx >= 0 && xx < WW);
    pp[kk] = yy * WW + xx;
    float s = 0.f;
    if (val[kk]) {
#pragma unroll
      for (int c = 0; c < CH; c++) s = fmaf(q[c], Kn[c * PP + pp[kk]], s);
    }
    f[kk] = s;
  }
  // PE (dw*pw folded) + softmax over 9
  float g[9], m = -1e30f;
#pragma unroll
  for (int k2 = 0; k2 < 9; k2++) {
    float s = 0.f;
#pragma unroll
    for (int kk = 0; kk < 9; kk++) s = fmaf(coef[k2 * 9 + kk], f[kk], s);
    g[k2] = s;
    m = fmaxf(m, s);
  }
  float ssum = 0.f;
#pragma unroll
  for (int k2 = 0; k2 < 9; k2++) {
    g[k2] = __expf(g[k2] - m);
    ssum += g[k2];
  }
  float inv = 1.f / ssum;
#pragma unroll
  for (int k2 = 0; k2 < 9; k2++) g[k2] *= inv;
  // O = sum_k s[k] * V[neighbor k]
#pragma unroll
  for (int c = 0; c < CH; c++) {
    float o = 0.f;
#pragma unroll
    for (int kk = 0; kk < 9; kk++) {
      if (val[kk]) o = fmaf(g[kk], Vn[c * PP + pp[kk]], o);
    }
    Qn[c * PP + p] = o;
  }
}

// ---------------------------------------------------------------------------
extern "C" void kernel_launch(void* const* d_in, const int* in_sizes, int n_in,
                              void* d_out, int out_size, void* d_ws, size_t ws_size,
                              hipStream_t stream) {
  const float* q     = (const float*)d_in[0];
  const float* k     = (const float*)d_in[1];
  const float* v     = (const float*)d_in[2];
  const float* wq    = (const float*)d_in[3];
  const float* pe_dw = (const float*)d_in[4];
  const float* pe_pw = (const float*)d_in[5];
  const float* wo    = (const float*)d_in[6];
  const float* bo    = (const float*)d_in[7];
  float* out = (float*)d_out;

  const size_t seg = (size_t)BB * CCH * PP;  // floats per [B,C,H,W] tensor
  float* Qb = (float*)d_ws;
  float* Kb = Qb + seg;
  float* Vb = Kb + seg;

  dim3 gg(PP / 128, CCH / 128, BB);  // (72, 2, 4)
  gemm_oc<<<gg, 256, 0, stream>>>(wq, q, Qb, nullptr);
  gemm_oc<<<gg, 256, 0, stream>>>(wq, k, Kb, nullptr);
  gemm_oc<<<gg, 256, 0, stream>>>(wq, v, Vb, nullptr);

  attn_k<<<dim3(WW / 32, HH / 8, NN), 256, 0, stream>>>(Kb, Vb, Qb, pe_dw, pe_pw);

  gemm_oc<<<gg, 256, 0, stream>>>(wo, Qb, out, bo);
}